// Round 1
// baseline (349.244 us; speedup 1.0000x reference)
//
#include <hip/hip_runtime.h>
#include <math.h>

#define GAMMA_ 0.99f
#define GL_ (0.99f * 0.95f)

// ---------------------------------------------------------------------------
// Pass 1: per (chunk, column) reverse scan with zero carry.
// Emits: A = a_local at chunk start, B = prod(c) over chunk,
//        Sa=sum a_local, Sa2=sum a_local^2, SaP=sum a_local*P, SP=sum P,
//        SP2=sum P^2, mask = nonterminal bitmask (bit (t-s)).
// ---------------------------------------------------------------------------
__global__ __launch_bounds__(256)
void gae_pass1(const float* __restrict__ rw, const float* __restrict__ vv,
               const int* __restrict__ dn,
               float* __restrict__ A, float* __restrict__ B,
               float* __restrict__ Sa, float* __restrict__ Sa2,
               float* __restrict__ SaP, float* __restrict__ SP,
               float* __restrict__ SP2,
               unsigned long long* __restrict__ mask,
               int T, int N, int L)
{
    int n = blockIdx.x * blockDim.x + threadIdx.x;
    int chunk = blockIdx.y;
    if (n >= N) return;
    int s = chunk * L;
    int e = s + L; if (e > T) e = T;
    int idx = chunk * N + n;
    if (s >= T) {  // degenerate chunk: identity combine, zero stats
        A[idx] = 0.f; B[idx] = 1.f;
        Sa[idx] = 0.f; Sa2[idx] = 0.f; SaP[idx] = 0.f; SP[idx] = 0.f; SP2[idx] = 0.f;
        mask[idx] = 0ull;
        return;
    }
    float a = 0.f, P = 1.f;
    float sa = 0.f, sa2 = 0.f, saP = 0.f, sP = 0.f, sP2 = 0.f;
    unsigned long long m = 0ull;
    float vnext = vv[(size_t)e * N + n];
    for (int t = e - 1; t >= s; --t) {
        size_t off = (size_t)t * N + n;
        float nt = (dn[off] == 0) ? 1.0f : 0.0f;
        float vc = vv[off];
        float delta = rw[off] + GAMMA_ * vnext * nt - vc;
        float c = GL_ * nt;
        a = delta + c * a;      // a_local[t]
        P = c * P;              // P[t] = prod c[t..e-1]
        sa += a; sa2 += a * a; saP += a * P; sP += P; sP2 += P * P;
        m |= ((unsigned long long)(nt != 0.f)) << (t - s);
        vnext = vc;
    }
    A[idx] = a; B[idx] = P;
    Sa[idx] = sa; Sa2[idx] = sa2; SaP[idx] = saP; SP[idx] = sP; SP2[idx] = sP2;
    mask[idx] = m;
}

// ---------------------------------------------------------------------------
// Pass 2: per-column carry propagation (last chunk -> first), exact global
// sum / sumsq via the algebraic decomposition, reduced in double.
// ---------------------------------------------------------------------------
__global__ __launch_bounds__(256)
void gae_pass2(const float* __restrict__ A, const float* __restrict__ B,
               const float* __restrict__ Sa, const float* __restrict__ Sa2,
               const float* __restrict__ SaP, const float* __restrict__ SP,
               const float* __restrict__ SP2,
               float* __restrict__ carry, double* __restrict__ sums,
               int N, int C)
{
    int n = blockIdx.x * blockDim.x + threadIdx.x;
    double lsum = 0.0, lsq = 0.0;
    if (n < N) {
        float g = 0.f;  // a_true at end of current chunk
        for (int i = C - 1; i >= 0; --i) {
            int idx = i * N + n;
            carry[idx] = g;
            float e = g;
            lsum += (double)(Sa[idx] + SP[idx] * e);
            lsq  += (double)(Sa2[idx] + 2.0f * e * SaP[idx] + (e * e) * SP2[idx]);
            g = A[idx] + B[idx] * g;  // a_true at start of chunk i
        }
    }
    __shared__ double sh[512];
    sh[threadIdx.x] = lsum;
    sh[256 + threadIdx.x] = lsq;
    __syncthreads();
    for (int off = 128; off > 0; off >>= 1) {
        if ((int)threadIdx.x < off) {
            sh[threadIdx.x] += sh[threadIdx.x + off];
            sh[256 + threadIdx.x] += sh[256 + threadIdx.x + off];
        }
        __syncthreads();
    }
    if (threadIdx.x == 0) {
        atomicAdd(&sums[0], sh[0]);
        atomicAdd(&sums[1], sh[256]);
    }
}

// ---------------------------------------------------------------------------
// Pass 3: redo the scan seeded with the true carry; normalize and emit
// advantages_norm and returns. Dones come from the 1-bit mask (62 MiB saved).
// ---------------------------------------------------------------------------
__global__ __launch_bounds__(256)
void gae_pass3(const float* __restrict__ rw, const float* __restrict__ vv,
               const unsigned long long* __restrict__ mask,
               const float* __restrict__ carry, const double* __restrict__ sums,
               float* __restrict__ out_adv, float* __restrict__ out_ret,
               int T, int N, int L, double Minv, double Mm1inv)
{
    int n = blockIdx.x * blockDim.x + threadIdx.x;
    int chunk = blockIdx.y;
    if (n >= N) return;
    int s = chunk * L;
    if (s >= T) return;
    int e = s + L; if (e > T) e = T;

    double S = sums[0], S2 = sums[1];
    double meand = S * Minv;
    double vard = (S2 - S * S * Minv) * Mm1inv;
    float mean = (float)meand;
    float inv = (float)(1.0 / (sqrt(vard) + 1e-8));

    int idx = chunk * N + n;
    float a = carry[idx];
    unsigned long long m = mask[idx];
    float vnext = vv[(size_t)e * N + n];
    for (int t = e - 1; t >= s; --t) {
        size_t off = (size_t)t * N + n;
        float nt = (float)((m >> (t - s)) & 1ull);
        float vc = vv[off];
        float delta = rw[off] + GAMMA_ * vnext * nt - vc;
        a = delta + GL_ * nt * a;       // true advantage at t
        out_adv[off] = (a - mean) * inv;
        out_ret[off] = a + vc;
        vnext = vc;
    }
}

extern "C" void kernel_launch(void* const* d_in, const int* in_sizes, int n_in,
                              void* d_out, int out_size, void* d_ws, size_t ws_size,
                              hipStream_t stream)
{
    const float* rw = (const float*)d_in[0];
    const float* vv = (const float*)d_in[1];
    const int*   dn = (const int*)d_in[2];

    long long TN = in_sizes[0];          // T*N
    long long VN = in_sizes[1];          // (T+1)*N
    int N = (int)(VN - TN);
    int T = (int)(TN / N);
    int L = 64;                          // chunk length (mask fits in u64)
    int C = (T + L - 1) / L;             // 32 for T=2048

    // Workspace layout: [2 doubles][mask: C*N u64][8 float arrays of C*N]
    char* ws = (char*)d_ws;
    double* sums = (double*)ws;
    size_t cn = (size_t)C * N;
    unsigned long long* mask = (unsigned long long*)(ws + 16);
    float* f   = (float*)(ws + 16 + cn * 8);
    float* A   = f;
    float* B   = f + cn;
    float* Sa  = f + 2 * cn;
    float* Sa2 = f + 3 * cn;
    float* SaP = f + 4 * cn;
    float* SP  = f + 5 * cn;
    float* SP2 = f + 6 * cn;
    float* cry = f + 7 * cn;

    hipMemsetAsync(d_ws, 0, 16, stream);   // zero the double accumulators

    dim3 blk(256);
    dim3 g1((N + 255) / 256, C);
    gae_pass1<<<g1, blk, 0, stream>>>(rw, vv, dn, A, B, Sa, Sa2, SaP, SP, SP2,
                                      mask, T, N, L);
    gae_pass2<<<dim3((N + 255) / 256), blk, 0, stream>>>(A, B, Sa, Sa2, SaP, SP,
                                                         SP2, cry, sums, N, C);
    double M = (double)TN;
    gae_pass3<<<g1, blk, 0, stream>>>(rw, vv, mask, cry, sums,
                                      (float*)d_out, (float*)d_out + TN,
                                      T, N, L, 1.0 / M, 1.0 / (M - 1.0));
}

// Round 2
// 329.019 us; speedup vs baseline: 1.0615x; 1.0615x over previous
//
#include <hip/hip_runtime.h>
#include <math.h>

#define GAMMA_ 0.99f
#define GL_ (0.99f * 0.95f)
#define L_ 32            // chunk length (mask fits in u32)

// ---------------------------------------------------------------------------
// Pass 1: per (chunk, column-quad) reverse scan with zero carry, 4 columns
// per thread via float4. Emits per-chunk affine summary (A,B) and the
// stats (Sa, Sa2, SaP, SP, SP2) needed to recombine global sum/sumsq, plus
// a 1-bit-per-step nonterminal mask so pass3 need not re-read dones.
// ---------------------------------------------------------------------------
__global__ __launch_bounds__(256)
void gae_pass1(const float4* __restrict__ rw, const float4* __restrict__ vv,
               const int4* __restrict__ dn,
               float4* __restrict__ A, float4* __restrict__ B,
               float4* __restrict__ Sa, float4* __restrict__ Sa2,
               float4* __restrict__ SaP, float4* __restrict__ SP,
               float4* __restrict__ SP2, uint4* __restrict__ mask,
               int T, int N4)
{
    int q = blockIdx.x * blockDim.x + threadIdx.x;   // column-quad index
    int chunk = blockIdx.y;
    if (q >= N4) return;
    int s = chunk * L_;
    int e = s + L_; if (e > T) e = T;

    float a[4] = {0.f,0.f,0.f,0.f}, P[4] = {1.f,1.f,1.f,1.f};
    float sa[4] = {0.f,0.f,0.f,0.f}, sa2[4] = {0.f,0.f,0.f,0.f};
    float saP[4] = {0.f,0.f,0.f,0.f}, sP[4] = {0.f,0.f,0.f,0.f};
    float sP2[4] = {0.f,0.f,0.f,0.f};
    unsigned mm[4] = {0u,0u,0u,0u};

    float4 vn4 = vv[(size_t)e * N4 + q];
    float vnext[4] = {vn4.x, vn4.y, vn4.z, vn4.w};

    #pragma unroll 2
    for (int t = e - 1; t >= s; --t) {
        size_t off = (size_t)t * N4 + q;
        float4 r4 = rw[off];
        int4   d4 = dn[off];
        float4 v4 = vv[off];
        float rr[4] = {r4.x, r4.y, r4.z, r4.w};
        int   dd[4] = {d4.x, d4.y, d4.z, d4.w};
        float vc[4] = {v4.x, v4.y, v4.z, v4.w};
        unsigned bit = 1u << (t - s);
        #pragma unroll
        for (int j = 0; j < 4; ++j) {
            float nt = (dd[j] == 0) ? 1.0f : 0.0f;
            float delta = rr[j] + GAMMA_ * vnext[j] * nt - vc[j];
            float c = GL_ * nt;
            a[j] = delta + c * a[j];
            P[j] = c * P[j];
            sa[j]  += a[j];
            sa2[j] += a[j] * a[j];
            saP[j] += a[j] * P[j];
            sP[j]  += P[j];
            sP2[j] += P[j] * P[j];
            if (dd[j] == 0) mm[j] |= bit;
            vnext[j] = vc[j];
        }
    }
    size_t idx = (size_t)chunk * N4 + q;
    A[idx]   = make_float4(a[0], a[1], a[2], a[3]);
    B[idx]   = make_float4(P[0], P[1], P[2], P[3]);
    Sa[idx]  = make_float4(sa[0], sa[1], sa[2], sa[3]);
    Sa2[idx] = make_float4(sa2[0], sa2[1], sa2[2], sa2[3]);
    SaP[idx] = make_float4(saP[0], saP[1], saP[2], saP[3]);
    SP[idx]  = make_float4(sP[0], sP[1], sP[2], sP[3]);
    SP2[idx] = make_float4(sP2[0], sP2[1], sP2[2], sP2[3]);
    mask[idx] = make_uint4(mm[0], mm[1], mm[2], mm[3]);
}

// ---------------------------------------------------------------------------
// Pass 2: per-column carry propagation (last chunk -> first); exact global
// sum / sumsq via the algebraic decomposition, reduced in double.
// Thread-per-column: all loads coalesced across lanes.
// ---------------------------------------------------------------------------
__global__ __launch_bounds__(64)
void gae_pass2(const float* __restrict__ A, const float* __restrict__ B,
               const float* __restrict__ Sa, const float* __restrict__ Sa2,
               const float* __restrict__ SaP, const float* __restrict__ SP,
               const float* __restrict__ SP2,
               float* __restrict__ carry, double* __restrict__ sums,
               int N, int C)
{
    int n = blockIdx.x * blockDim.x + threadIdx.x;
    double lsum = 0.0, lsq = 0.0;
    if (n < N) {
        float g = 0.f;  // true advantage carry at end of current chunk
        for (int i = C - 1; i >= 0; --i) {
            int idx = i * N + n;
            carry[idx] = g;
            float e = g;
            lsum += (double)(Sa[idx] + SP[idx] * e);
            lsq  += (double)(Sa2[idx] + 2.0f * e * SaP[idx] + (e * e) * SP2[idx]);
            g = A[idx] + B[idx] * g;
        }
    }
    // wave64 butterfly reduction, one atomic pair per wave
    for (int off = 32; off > 0; off >>= 1) {
        lsum += __shfl_down(lsum, off, 64);
        lsq  += __shfl_down(lsq, off, 64);
    }
    if ((threadIdx.x & 63) == 0) {
        atomicAdd(&sums[0], lsum);
        atomicAdd(&sums[1], lsq);
    }
}

// ---------------------------------------------------------------------------
// Pass 3: redo the scan seeded with the true carry; normalize and emit
// advantages_norm and returns, 4 columns per thread, float4 stores.
// ---------------------------------------------------------------------------
__global__ __launch_bounds__(256)
void gae_pass3(const float4* __restrict__ rw, const float4* __restrict__ vv,
               const uint4* __restrict__ mask, const float4* __restrict__ carry,
               const double* __restrict__ sums,
               float4* __restrict__ out_adv, float4* __restrict__ out_ret,
               int T, int N4, double Minv, double Mm1inv)
{
    int q = blockIdx.x * blockDim.x + threadIdx.x;
    int chunk = blockIdx.y;
    if (q >= N4) return;
    int s = chunk * L_;
    int e = s + L_; if (e > T) e = T;

    double S = sums[0], S2 = sums[1];
    float mean = (float)(S * Minv);
    double vard = (S2 - S * S * Minv) * Mm1inv;
    float inv = (float)(1.0 / (sqrt(vard) + 1e-8));

    size_t idx = (size_t)chunk * N4 + q;
    float4 c4 = carry[idx];
    uint4  m4 = mask[idx];
    float a[4] = {c4.x, c4.y, c4.z, c4.w};
    unsigned mm[4] = {m4.x, m4.y, m4.z, m4.w};

    float4 vn4 = vv[(size_t)e * N4 + q];
    float vnext[4] = {vn4.x, vn4.y, vn4.z, vn4.w};

    #pragma unroll 2
    for (int t = e - 1; t >= s; --t) {
        size_t off = (size_t)t * N4 + q;
        float4 r4 = rw[off];
        float4 v4 = vv[off];
        float rr[4] = {r4.x, r4.y, r4.z, r4.w};
        float vc[4] = {v4.x, v4.y, v4.z, v4.w};
        float oa[4], orr[4];
        unsigned bit = 1u << (t - s);
        #pragma unroll
        for (int j = 0; j < 4; ++j) {
            float nt = (mm[j] & bit) ? 1.0f : 0.0f;
            float delta = rr[j] + GAMMA_ * vnext[j] * nt - vc[j];
            a[j] = delta + GL_ * nt * a[j];
            oa[j]  = (a[j] - mean) * inv;
            orr[j] = a[j] + vc[j];
            vnext[j] = vc[j];
        }
        out_adv[off] = make_float4(oa[0], oa[1], oa[2], oa[3]);
        out_ret[off] = make_float4(orr[0], orr[1], orr[2], orr[3]);
    }
}

extern "C" void kernel_launch(void* const* d_in, const int* in_sizes, int n_in,
                              void* d_out, int out_size, void* d_ws, size_t ws_size,
                              hipStream_t stream)
{
    const float* rw = (const float*)d_in[0];
    const float* vv = (const float*)d_in[1];
    const int*   dn = (const int*)d_in[2];

    long long TN = in_sizes[0];          // T*N
    long long VN = in_sizes[1];          // (T+1)*N
    int N = (int)(VN - TN);
    int T = (int)(TN / N);
    int N4 = N / 4;
    int C = (T + L_ - 1) / L_;           // 64 for T=2048

    // Workspace: [2 doubles][mask: C*N u32][8 float arrays of C*N]
    char* ws = (char*)d_ws;
    double* sums = (double*)ws;
    size_t cn = (size_t)C * N;
    unsigned* mask = (unsigned*)(ws + 16);
    float* f   = (float*)(ws + 16 + cn * 4);
    float* A   = f;
    float* B   = f + cn;
    float* Sa  = f + 2 * cn;
    float* Sa2 = f + 3 * cn;
    float* SaP = f + 4 * cn;
    float* SP  = f + 5 * cn;
    float* SP2 = f + 6 * cn;
    float* cry = f + 7 * cn;

    hipMemsetAsync(d_ws, 0, 16, stream);   // zero the double accumulators

    dim3 blk(256);
    dim3 g1((N4 + 255) / 256, C);
    gae_pass1<<<g1, blk, 0, stream>>>(
        (const float4*)rw, (const float4*)vv, (const int4*)dn,
        (float4*)A, (float4*)B, (float4*)Sa, (float4*)Sa2, (float4*)SaP,
        (float4*)SP, (float4*)SP2, (uint4*)mask, T, N4);

    gae_pass2<<<dim3((N + 63) / 64), dim3(64), 0, stream>>>(
        A, B, Sa, Sa2, SaP, SP, SP2, cry, sums, N, C);

    double M = (double)TN;
    gae_pass3<<<g1, blk, 0, stream>>>(
        (const float4*)rw, (const float4*)vv, (const uint4*)mask,
        (const float4*)cry, sums,
        (float4*)d_out, (float4*)((float*)d_out + TN),
        T, N4, 1.0 / M, 1.0 / (M - 1.0));
}